// Round 6
// baseline (109.229 us; speedup 1.0000x reference)
//
#include <hip/hip_runtime.h>

#define NUM_WIRES 4
#define NUM_LAYERS 2

// R10: DIAGNOSTIC round 2. R9 (2x body) measured the marginal body cost at
// 16.8us (dur 79.2 -> 96.0) => CPI ~4.7 vs the ~2 cyc/inst issue floor, but
// qsim at ~44.5us fell JUST under the ~45.5us harness fills and still missed
// the top-5 counter rows -- VGPR/Occupancy/VALUBusy remain unmeasured, and
// they discriminate the three CPI hypotheses (occupancy-starved latency vs
// hidden inst bloat vs structural stall). This round runs the body 3x
// (two perturbed + asm-sunk per rule #17, final true + stored): qsim
// ~61us > fills -> guaranteed visible counter row. Output bit-identical.
//
// Next round applies the indicated fix to the R7 single-body base (78.6us).
//
// LDS g[] layout (floats):
//  [ 0..15]  layer-0 per wire w: {A=cx*cz, B=cx*sz, C=sx*sz, D=sx*cz}
//  [16..23]  layer-1 RX per wire: {cos, sin}
//  [24..55]  layer-1 combined RZ diagonal: 16 x {dr, di}
//
// State layout: amp[i], bit3=wire0 ... bit0=wire3 (reference (B,2,2,2,2) order).

#define INV_4PI 0.07957747154594767f  // 0.5 / (2*pi): sin(0.5x) = v_sin(x * INV_4PI)

__device__ __forceinline__ float rfl(float v) {
    return __int_as_float(__builtin_amdgcn_readfirstlane(__float_as_int(v)));
}

__device__ __forceinline__ void cmul(float ar, float ai, float br, float bi,
                                     float& orr, float& oi) {
    orr = fmaf(ar, br, -(ai * bi));
    oi  = fmaf(ar, bi,   ai * br);
}

template <int CM, int TM>
__device__ __forceinline__ void cnot(float zr[16], float zi[16]) {
#pragma unroll
    for (int i = 0; i < 16; ++i) {
        if ((i & CM) && !(i & TM)) {
            const int j = i | TM;
            float t;
            t = zr[i]; zr[i] = zr[j]; zr[j] = t;
            t = zi[i]; zi[i] = zi[j]; zi[j] = t;
        }
    }
}

__device__ __forceinline__ float4 qsim_body(const float4 xv, const float* __restrict__ G) {
    // Layer-0: fused gate applied to each wire's RY(x)|0> = (c,s) factor.
    float fr[4][2], fi[4][2];
    {
        const float xs[4] = {xv.x, xv.y, xv.z, xv.w};
#pragma unroll
        for (int w = 0; w < 4; ++w) {
            const float r = xs[w] * INV_4PI;
            const float s = __builtin_amdgcn_sinf(r);
            const float c = __builtin_amdgcn_cosf(r);
            const float A = G[w * 4 + 0], B = G[w * 4 + 1];
            const float C = G[w * 4 + 2], D = G[w * 4 + 3];
            fr[w][0] = fmaf(A, c, C * s);      // u00r*c + u01r*s
            fi[w][0] = fmaf(-B, c, -(D * s));  // u00i*c + u01i*s
            fr[w][1] = fmaf(A, s, -(C * c));   // u10r*c + u11r*s
            fi[w][1] = fmaf(B, s, -(D * c));   // u10i*c + u11i*s
        }
    }

    // Complex outer product: z = (f0 (x) f1) (x) (f2 (x) f3)
    float mr[4], mi[4], nr[4], ni[4];
#pragma unroll
    for (int p = 0; p < 2; ++p)
#pragma unroll
        for (int q = 0; q < 2; ++q) {
            cmul(fr[0][p], fi[0][p], fr[1][q], fi[1][q], mr[p * 2 + q], mi[p * 2 + q]);
            cmul(fr[2][p], fi[2][p], fr[3][q], fi[3][q], nr[p * 2 + q], ni[p * 2 + q]);
        }
    float zr[16], zi[16];
#pragma unroll
    for (int i = 0; i < 16; ++i)
        cmul(mr[i >> 2], mi[i >> 2], nr[i & 3], ni[i & 3], zr[i], zi[i]);

    // Layer-0 CNOT ring (free register permutation)
    cnot<8, 4>(zr, zi);
    cnot<4, 2>(zr, zi);
    cnot<2, 1>(zr, zi);
    cnot<1, 8>(zr, zi);

    // Layer-1 combined RZ diagonal
#pragma unroll
    for (int i = 0; i < 16; ++i) {
        const float dr = G[24 + i * 2], di = G[25 + i * 2];
        const float ar = zr[i], ai = zi[i];
        zr[i] = fmaf(dr, ar, -(di * ai));
        zi[i] = fmaf(dr, ai,   di * ar);
    }

    // Layer-1 RX per wire: new_a = c*a - i*s*b -> (c*ar + s*bi, c*ai - s*br)
#pragma unroll
    for (int w = 0; w < 4; ++w) {
        const float c = G[16 + w * 2], s = G[17 + w * 2];
        const int M = 8 >> w;
#pragma unroll
        for (int i = 0; i < 16; ++i) {
            if (!(i & M)) {
                const int j = i | M;
                const float ar = zr[i], ai = zi[i];
                const float br = zr[j], bi = zi[j];
                zr[i] = fmaf(c, ar,   s * bi);
                zi[i] = fmaf(c, ai, -(s * br));
                zr[j] = fmaf(c, br,   s * ai);
                zi[j] = fmaf(c, bi, -(s * ar));
            }
        }
    }

    // Layer-1 CNOT ring
    cnot<8, 4>(zr, zi);
    cnot<4, 2>(zr, zi);
    cnot<2, 1>(zr, zi);
    cnot<1, 8>(zr, zi);

    // Probabilities and <Z_w> via sum/difference tree
    float p[16];
#pragma unroll
    for (int i = 0; i < 16; ++i) p[i] = fmaf(zr[i], zr[i], zi[i] * zi[i]);

    float d0[8], s1[8];
#pragma unroll
    for (int k = 0; k < 8; ++k) {
        d0[k] = p[2 * k] - p[2 * k + 1];
        s1[k] = p[2 * k] + p[2 * k + 1];
    }
    const float e3 = ((d0[0] + d0[1]) + (d0[2] + d0[3])) + ((d0[4] + d0[5]) + (d0[6] + d0[7]));
    const float e2 = ((s1[0] - s1[1]) + (s1[2] - s1[3])) + ((s1[4] - s1[5]) + (s1[6] - s1[7]));
    float s2[4];
#pragma unroll
    for (int k = 0; k < 4; ++k) s2[k] = s1[2 * k] + s1[2 * k + 1];
    const float e1 = (s2[0] - s2[1]) + (s2[2] - s2[3]);
    const float e0 = (s2[0] + s2[1]) - (s2[2] + s2[3]);

    return make_float4(e0, e1, e2, e3);
}

__global__ __launch_bounds__(256) void qsim_kernel(const float* __restrict__ x,
                                                   const float* __restrict__ params,
                                                   float* __restrict__ out, int batch) {
    __shared__ float g[64];  // 56 used

    // --- Per-block gate prep (first wave only; once per block) ---
    const int t = threadIdx.x;
    if (t < 32) {
        if (t < 4) {
            const float p0 = params[t * 2 + 0];  // RZ
            const float p1 = params[t * 2 + 1];  // RX
            float cz, sz, cx, sx;
            __sincosf(0.5f * p0, &sz, &cz);
            __sincosf(0.5f * p1, &sx, &cx);
            g[t * 4 + 0] = cx * cz;
            g[t * 4 + 1] = cx * sz;
            g[t * 4 + 2] = sx * sz;
            g[t * 4 + 3] = sx * cz;
        } else if (t < 8) {
            const int w = t - 4;
            const float p1 = params[(NUM_WIRES + w) * 2 + 1];
            float cx, sx;
            __sincosf(0.5f * p1, &sx, &cx);
            g[16 + w * 2] = cx;
            g[17 + w * 2] = sx;
        } else if (t >= 16) {
            const int i = t - 16;
            float dr = 1.f, di = 0.f;
            for (int w = 0; w < NUM_WIRES; ++w) {
                const float p0 = params[(NUM_WIRES + w) * 2 + 0];
                float c, s;
                __sincosf(0.5f * p0, &s, &c);
                const float sg = ((i >> (3 - w)) & 1) ? s : -s;
                const float ndr = dr * c - di * sg;
                const float ndi = dr * sg + di * c;
                dr = ndr; di = ndi;
            }
            g[24 + i * 2] = dr;
            g[25 + i * 2] = di;
        }
    }
    __syncthreads();

    // --- Pull all 56 batch-uniform constants into SGPRs via LDS broadcast ---
    float G[56];
#pragma unroll
    for (int k = 0; k < 14; ++k) {
        const float4 v = reinterpret_cast<const float4*>(g)[k];
        G[4 * k + 0] = rfl(v.x);
        G[4 * k + 1] = rfl(v.y);
        G[4 * k + 2] = rfl(v.z);
        G[4 * k + 3] = rfl(v.w);
    }

    const int b = blockIdx.x * 256 + threadIdx.x;
    if (b >= batch) return;  // after the barrier: no deadlock hazard

    const float4 xv = reinterpret_cast<const float4*>(x)[b];

    // DIAGNOSTIC: run the body 3x. Iters 0,1: perturbed input, results kept
    // live via asm sink (no DCE, rule #17). Iter 2: true input -> stored.
    float4 res;
#pragma unroll 1
    for (int it = 0; it < 3; ++it) {
        float4 in = xv;
        if (it == 0) {
            in.x *= 1.0002441f; in.y *= 1.0002441f;
            in.z *= 1.0002441f; in.w *= 1.0002441f;
        } else if (it == 1) {
            in.x *= 0.9997559f; in.y *= 0.9997559f;
            in.z *= 0.9997559f; in.w *= 0.9997559f;
        }
        res = qsim_body(in, G);
        if (it < 2) {
            asm volatile("" :: "v"(res.x), "v"(res.y), "v"(res.z), "v"(res.w));
        }
    }

    reinterpret_cast<float4*>(out)[b] = res;
}

extern "C" void kernel_launch(void* const* d_in, const int* in_sizes, int n_in,
                              void* d_out, int out_size, void* d_ws, size_t ws_size,
                              hipStream_t stream) {
    const float* x = (const float*)d_in[0];        // (B, 4) float32
    const float* params = (const float*)d_in[1];   // (2, 4, 2) float32
    float* out = (float*)d_out;                    // (B, 4) float32
    const int batch = in_sizes[0] / NUM_WIRES;

    const int blocks = (batch + 255) / 256;
    qsim_kernel<<<blocks, 256, 0, stream>>>(x, params, out, batch);
}

// Round 7
// 78.445 us; speedup vs baseline: 1.3924x; 1.3924x over previous
//
#include <hip/hip_runtime.h>

#define NUM_WIRES 4
#define NUM_LAYERS 2

// R11: branch-free / barrier-free / LDS-free preamble.
// R10 diagnostics (qsim visible: VGPR=52, VALUBusy~74%, Occupancy~36%) killed
// the register-pressure hypothesis and pointed at the block prologue: wave 0
// ran a divergent OCML-__sincosf prep (~500+ serial cycles) while 3 waves
// waited at __syncthreads, then all waves paid 14 ds_read + 56 rfl.
// Now EVERY lane computes the constants in parallel by lane id with native
// v_sin/v_cos (no branches, no barrier, no LDS):
//   lane&3  -> that wire's layer-0 fused consts {A,B,C,D} + layer-1 RX {c,s}
//   lane&15 -> that entry of the 16-element combined layer-1 RZ diagonal
// then 56 x v_readlane (immediate lane) fills the SGPR-resident G[56] the
// verified body consumes unchanged. Single body per thread (R8 structure).
//
// G[] layout (floats):
//  [ 0..15]  layer-0 per wire w: {A=cx*cz, B=cx*sz, C=sx*sz, D=sx*cz}
//  [16..23]  layer-1 RX per wire: {cos, sin}
//  [24..55]  layer-1 combined RZ diagonal: 16 x {dr, di}
//
// State layout: amp[i], bit3=wire0 ... bit0=wire3 (reference (B,2,2,2,2) order).

#define INV_4PI 0.07957747154594767f  // 0.5 / (2*pi): sin(0.5x) = v_sin(x * INV_4PI)

__device__ __forceinline__ float RL(float v, int lane) {
    return __int_as_float(__builtin_amdgcn_readlane(__float_as_int(v), lane));
}

__device__ __forceinline__ void cmul(float ar, float ai, float br, float bi,
                                     float& orr, float& oi) {
    orr = fmaf(ar, br, -(ai * bi));
    oi  = fmaf(ar, bi,   ai * br);
}

template <int CM, int TM>
__device__ __forceinline__ void cnot(float zr[16], float zi[16]) {
#pragma unroll
    for (int i = 0; i < 16; ++i) {
        if ((i & CM) && !(i & TM)) {
            const int j = i | TM;
            float t;
            t = zr[i]; zr[i] = zr[j]; zr[j] = t;
            t = zi[i]; zi[i] = zi[j]; zi[j] = t;
        }
    }
}

__global__ __launch_bounds__(256) void qsim_kernel(const float* __restrict__ x,
                                                   const float* __restrict__ params,
                                                   float* __restrict__ out, int batch) {
    const int L = threadIdx.x & 63;
    const int w = L & 3;
    const int di = L & 15;

    // params (16 floats), uniform addresses -> scalarizable broadcast loads.
    const float4 P0 = reinterpret_cast<const float4*>(params)[0];  // L0 w0,w1: {z,x,z,x}
    const float4 P1 = reinterpret_cast<const float4*>(params)[1];  // L0 w2,w3
    const float4 P2 = reinterpret_cast<const float4*>(params)[2];  // L1 w0,w1
    const float4 P3 = reinterpret_cast<const float4*>(params)[3];  // L1 w2,w3

    // --- my-wire (w = L&3) layer-0 params, layer-1 RX param ---
    const float pz0 = (w == 0) ? P0.x : (w == 1) ? P0.z : (w == 2) ? P1.x : P1.z;
    const float px0 = (w == 0) ? P0.y : (w == 1) ? P0.w : (w == 2) ? P1.y : P1.w;
    const float px1 = (w == 0) ? P2.y : (w == 1) ? P2.w : (w == 2) ? P3.y : P3.w;

    // layer-0 fused consts (native trig; |0.5p|/2pi << 0.5 for N(0,1) params)
    const float rz = pz0 * INV_4PI;
    const float sz = __builtin_amdgcn_sinf(rz), cz = __builtin_amdgcn_cosf(rz);
    const float rx = px0 * INV_4PI;
    const float sx = __builtin_amdgcn_sinf(rx), cx = __builtin_amdgcn_cosf(rx);
    const float vA = cx * cz, vB = cx * sz, vC = sx * sz, vD = sx * cz;

    // layer-1 RX consts
    const float rx1 = px1 * INV_4PI;
    const float vS1 = __builtin_amdgcn_sinf(rx1), vC1 = __builtin_amdgcn_cosf(rx1);

    // --- my diag entry (di = L&15): prod over wires of (c_w + i*sg_w) ---
    float ddr, ddi;
    {
        const float z0 = P2.x * INV_4PI, z1 = P2.z * INV_4PI;
        const float z2 = P3.x * INV_4PI, z3 = P3.z * INV_4PI;
        const float c0 = __builtin_amdgcn_cosf(z0), s0 = __builtin_amdgcn_sinf(z0);
        const float c1 = __builtin_amdgcn_cosf(z1), s1 = __builtin_amdgcn_sinf(z1);
        const float c2 = __builtin_amdgcn_cosf(z2), s2 = __builtin_amdgcn_sinf(z2);
        const float c3 = __builtin_amdgcn_cosf(z3), s3 = __builtin_amdgcn_sinf(z3);
        const float g0 = (di & 8) ? s0 : -s0;  // bit (3-w'): w'=0 -> bit3
        const float g1 = (di & 4) ? s1 : -s1;
        const float g2 = (di & 2) ? s2 : -s2;
        const float g3 = (di & 1) ? s3 : -s3;
        ddr = c0; ddi = g0;
        float t;
        t = ddr * c1 - ddi * g1; ddi = fmaf(ddr, g1, ddi * c1); ddr = t;
        t = ddr * c2 - ddi * g2; ddi = fmaf(ddr, g2, ddi * c2); ddr = t;
        t = ddr * c3 - ddi * g3; ddi = fmaf(ddr, g3, ddi * c3); ddr = t;
    }

    // --- gather all 56 batch-uniform constants into SGPRs via readlane ---
    float G[56];
#pragma unroll
    for (int q = 0; q < 4; ++q) {
        G[q * 4 + 0] = RL(vA, q);
        G[q * 4 + 1] = RL(vB, q);
        G[q * 4 + 2] = RL(vC, q);
        G[q * 4 + 3] = RL(vD, q);
        G[16 + q * 2] = RL(vC1, q);
        G[17 + q * 2] = RL(vS1, q);
    }
#pragma unroll
    for (int q = 0; q < 16; ++q) {
        G[24 + q * 2] = RL(ddr, q);
        G[25 + q * 2] = RL(ddi, q);
    }

    const int b = blockIdx.x * 256 + threadIdx.x;
    if (b >= batch) return;

    const float4 xv = reinterpret_cast<const float4*>(x)[b];

    // Layer-0: fused gate applied to each wire's RY(x)|0> = (c,s) factor.
    float fr[4][2], fi[4][2];
    {
        const float xs[4] = {xv.x, xv.y, xv.z, xv.w};
#pragma unroll
        for (int q = 0; q < 4; ++q) {
            const float r = xs[q] * INV_4PI;
            const float s = __builtin_amdgcn_sinf(r);
            const float c = __builtin_amdgcn_cosf(r);
            const float A = G[q * 4 + 0], B = G[q * 4 + 1];
            const float C = G[q * 4 + 2], D = G[q * 4 + 3];
            fr[q][0] = fmaf(A, c, C * s);      // u00r*c + u01r*s
            fi[q][0] = fmaf(-B, c, -(D * s));  // u00i*c + u01i*s
            fr[q][1] = fmaf(A, s, -(C * c));   // u10r*c + u11r*s
            fi[q][1] = fmaf(B, s, -(D * c));   // u10i*c + u11i*s
        }
    }

    // Complex outer product: z = (f0 (x) f1) (x) (f2 (x) f3)
    float mr[4], mi[4], nr[4], ni[4];
#pragma unroll
    for (int p = 0; p < 2; ++p)
#pragma unroll
        for (int q = 0; q < 2; ++q) {
            cmul(fr[0][p], fi[0][p], fr[1][q], fi[1][q], mr[p * 2 + q], mi[p * 2 + q]);
            cmul(fr[2][p], fi[2][p], fr[3][q], fi[3][q], nr[p * 2 + q], ni[p * 2 + q]);
        }
    float zr[16], zi[16];
#pragma unroll
    for (int i = 0; i < 16; ++i)
        cmul(mr[i >> 2], mi[i >> 2], nr[i & 3], ni[i & 3], zr[i], zi[i]);

    // Layer-0 CNOT ring (free register permutation)
    cnot<8, 4>(zr, zi);
    cnot<4, 2>(zr, zi);
    cnot<2, 1>(zr, zi);
    cnot<1, 8>(zr, zi);

    // Layer-1 combined RZ diagonal
#pragma unroll
    for (int i = 0; i < 16; ++i) {
        const float dr = G[24 + i * 2], dii = G[25 + i * 2];
        const float ar = zr[i], ai = zi[i];
        zr[i] = fmaf(dr, ar, -(dii * ai));
        zi[i] = fmaf(dr, ai,   dii * ar);
    }

    // Layer-1 RX per wire: new_a = c*a - i*s*b -> (c*ar + s*bi, c*ai - s*br)
#pragma unroll
    for (int q = 0; q < 4; ++q) {
        const float c = G[16 + q * 2], s = G[17 + q * 2];
        const int M = 8 >> q;
#pragma unroll
        for (int i = 0; i < 16; ++i) {
            if (!(i & M)) {
                const int j = i | M;
                const float ar = zr[i], ai = zi[i];
                const float br = zr[j], bi = zi[j];
                zr[i] = fmaf(c, ar,   s * bi);
                zi[i] = fmaf(c, ai, -(s * br));
                zr[j] = fmaf(c, br,   s * ai);
                zi[j] = fmaf(c, bi, -(s * ar));
            }
        }
    }

    // Layer-1 CNOT ring
    cnot<8, 4>(zr, zi);
    cnot<4, 2>(zr, zi);
    cnot<2, 1>(zr, zi);
    cnot<1, 8>(zr, zi);

    // Probabilities and <Z_w> via sum/difference tree
    float p[16];
#pragma unroll
    for (int i = 0; i < 16; ++i) p[i] = fmaf(zr[i], zr[i], zi[i] * zi[i]);

    float d0[8], s1[8];
#pragma unroll
    for (int k = 0; k < 8; ++k) {
        d0[k] = p[2 * k] - p[2 * k + 1];
        s1[k] = p[2 * k] + p[2 * k + 1];
    }
    const float e3 = ((d0[0] + d0[1]) + (d0[2] + d0[3])) + ((d0[4] + d0[5]) + (d0[6] + d0[7]));
    const float e2 = ((s1[0] - s1[1]) + (s1[2] - s1[3])) + ((s1[4] - s1[5]) + (s1[6] - s1[7]));
    float s2[4];
#pragma unroll
    for (int k = 0; k < 4; ++k) s2[k] = s1[2 * k] + s1[2 * k + 1];
    const float e1 = (s2[0] - s2[1]) + (s2[2] - s2[3]);
    const float e0 = (s2[0] + s2[1]) - (s2[2] + s2[3]);

    reinterpret_cast<float4*>(out)[b] = make_float4(e0, e1, e2, e3);
}

extern "C" void kernel_launch(void* const* d_in, const int* in_sizes, int n_in,
                              void* d_out, int out_size, void* d_ws, size_t ws_size,
                              hipStream_t stream) {
    const float* x = (const float*)d_in[0];        // (B, 4) float32
    const float* params = (const float*)d_in[1];   // (2, 4, 2) float32
    float* out = (float*)d_out;                    // (B, 4) float32
    const int batch = in_sizes[0] / NUM_WIRES;

    const int blocks = (batch + 255) / 256;
    qsim_kernel<<<blocks, 256, 0, stream>>>(x, params, out, batch);
}